// Round 5
// baseline (40.983 us; speedup 1.0000x reference)
//
#include <hip/hip_runtime.h>
#include <hip/hip_bf16.h>
#include <math.h>
#include <stdint.h>

#define NS 8192       // samples
#define DD 1024       // feature dim
#define NP 512        // prototypes
#define BK 64         // K-chunk
#define MT 32         // M rows per block
#define EPSF 1e-9f
#define BIGF 3.0e38f

typedef __attribute__((ext_vector_type(8))) short bf16x8;
typedef __attribute__((ext_vector_type(4))) float f32x4;

__device__ inline unsigned short f32_to_bf16(float f) {
    uint32_t u = __builtin_bit_cast(uint32_t, f);
    uint32_t r = (u + 0x7FFFu + ((u >> 16) & 1u)) >> 16;
    return (unsigned short)r;
}

// protos f32 -> bf16 (pb) + exact f32 psq. One block per prototype row.
__global__ __launch_bounds__(256) void prep_protos(
    const float* __restrict__ protos,
    unsigned short* __restrict__ pb, float* __restrict__ psq)
{
    const int row = blockIdx.x;
    const int t = threadIdx.x;
    float4 v = ((const float4*)(protos + (size_t)row * DD))[t];
    float ss = v.x * v.x + v.y * v.y + v.z * v.z + v.w * v.w;
    ushort4 o;
    o.x = f32_to_bf16(v.x); o.y = f32_to_bf16(v.y);
    o.z = f32_to_bf16(v.z); o.w = f32_to_bf16(v.w);
    ((ushort4*)(pb + (size_t)row * DD))[t] = o;
    for (int off = 32; off; off >>= 1) ss += __shfl_down(ss, off);
    __shared__ float red[4];
    if ((t & 63) == 0) red[t >> 6] = ss;
    __syncthreads();
    if (t == 0) psq[row] = red[0] + red[1] + red[2] + red[3];
}

// Fully fused: per block, 32 x-rows vs ALL 512 prototypes.
// x read ONCE as f32 (HBM stream), cvt->bf16 in-reg (exact f32 xsq on the fly).
// B (1 MB bf16) streamed from L2 via global_load_lds, XOR-swizzled LDS.
// Epilogue: masked mins -> mu -> sigmoid -> per-block sum. 8 waves (2 M x 4 N).
__global__ __launch_bounds__(512, 2) void glvq_fused(
    const float* __restrict__ x, const unsigned short* __restrict__ pb,
    const float* __restrict__ psq, const int* __restrict__ y,
    const int* __restrict__ tval, float* __restrict__ bsum)
{
    __shared__ unsigned short Bs[2][NP * BK];   // 2 x 64 KB
    __shared__ unsigned short As[2][MT * BK];   // 2 x 4 KB
    __shared__ float xs_l[MT];
    __shared__ float dpart[MT][4][2];

    const int tid  = threadIdx.x;
    const int lane = tid & 63;
    const int wid  = tid >> 6;        // 0..7
    const int wr = wid >> 2;          // 0..1 -> rows wr*16..+15
    const int wc = wid & 3;           // 0..3 -> cols wc*128..+127
    const int m0 = blockIdx.x * MT;

    const int srow   = lane >> 3;                 // 0..7
    const int scol16 = (lane & 7) ^ srow;         // pre-swizzled B source 16B-chunk
    const int sub = lane & 15, g = lane >> 4;

    // A staging: thread t covers row (t>>4), f32 cols (t&15)*4 .. +3
    const int arow   = tid >> 4;                  // 0..31
    const int acol4  = tid & 15;
    const int achunk = acol4 >> 1;                // 16B bf16 chunk 0..7
    const int alds_off = arow * 128 + ((achunk ^ (arow & 7)) * 16) + (acol4 & 1) * 8;
    const float* xrow = x + (size_t)(m0 + arow) * DD + acol4 * 4;

    f32x4 acc[8] = {};
    float xss = 0.0f;

    auto stageB = [&](int buf, int kt) {
        const int k0 = kt * BK;
#pragma unroll
        for (int j = 0; j < 8; ++j) {
            const int unit = wid * 8 + j;                   // 0..63, 8 B-rows each
            const unsigned short* gb = pb + (size_t)(unit * 8 + srow) * DD + k0 + scol16 * 8;
            __builtin_amdgcn_global_load_lds(
                (const __attribute__((address_space(1))) void*)gb,
                (__attribute__((address_space(3))) void*)((char*)&Bs[buf][0] + unit * 1024),
                16, 0, 0);
        }
    };
    auto writeA = [&](int buf, float4 v) {
        xss += v.x * v.x + v.y * v.y + v.z * v.z + v.w * v.w;
        ushort4 o;
        o.x = f32_to_bf16(v.x); o.y = f32_to_bf16(v.y);
        o.z = f32_to_bf16(v.z); o.w = f32_to_bf16(v.w);
        *(ushort4*)((char*)&As[buf][0] + alds_off) = o;
    };
    auto compute = [&](int buf) {
#pragma unroll
        for (int kk = 0; kk < 2; ++kk) {
            const int rowa = wr * 16 + sub;
            const int c16a = (kk * 4 + g) ^ (rowa & 7);
            bf16x8 a = *(const bf16x8*)((const char*)&As[buf][0] + rowa * 128 + c16a * 16);
            bf16x8 b[8];
#pragma unroll
            for (int n = 0; n < 8; ++n) {
                const int rowb = wc * 128 + n * 16 + sub;
                const int c16b = (kk * 4 + g) ^ (rowb & 7);
                b[n] = *(const bf16x8*)((const char*)&Bs[buf][0] + rowb * 128 + c16b * 16);
            }
#pragma unroll
            for (int n = 0; n < 8; ++n)
                acc[n] = __builtin_amdgcn_mfma_f32_16x16x32_bf16(a, b[n], acc[n], 0, 0, 0);
        }
    };

    // prologue
    stageB(0, 0);
    writeA(0, *(const float4*)(xrow));
    __syncthreads();

    int cur = 0;
#pragma unroll 1
    for (int kt = 0; kt < DD / BK - 1; ++kt) {
        stageB(cur ^ 1, kt + 1);                       // issue next B (stays in flight)
        float4 av = *(const float4*)(xrow + (kt + 1) * BK);  // issue next A
        compute(cur);                                  // MFMA covers load latency
        writeA(cur ^ 1, av);
        __syncthreads();
        cur ^= 1;
    }
    compute(cur);

    // exact xsq: reduce over the 16 staging threads of each row
    for (int off = 8; off; off >>= 1) xss += __shfl_xor(xss, off);
    if ((tid & 15) == 0) xs_l[arow] = xss;
    __syncthreads();

    // ---- epilogue: masked mins over this wave's 128 cols ----
    float psqv[8];
    int   lab[8];
#pragma unroll
    for (int n = 0; n < 8; ++n) {
        const int col = wc * 128 + n * 16 + sub;
        psqv[n] = psq[col];
        lab[n]  = col >> 2;
    }
#pragma unroll
    for (int r = 0; r < 4; ++r) {
        const int rl = wr * 16 + g * 4 + r;
        const float xs = xs_l[rl];
        const int yy = y[m0 + rl];
        float d1 = BIGF, d2 = BIGF;
#pragma unroll
        for (int n = 0; n < 8; ++n) {
            const float dist = xs + psqv[n] - 2.0f * acc[n][r];
            if (lab[n] == yy) d1 = fminf(d1, dist);
            else              d2 = fminf(d2, dist);
        }
        for (int off = 8; off; off >>= 1) {
            d1 = fminf(d1, __shfl_xor(d1, off));
            d2 = fminf(d2, __shfl_xor(d2, off));
        }
        if (sub == 0) { dpart[rl][wc][0] = d1; dpart[rl][wc][1] = d2; }
    }
    __syncthreads();

    if (tid < MT) {
        float d1 = BIGF, d2 = BIGF;
#pragma unroll
        for (int c = 0; c < 4; ++c) {
            d1 = fminf(d1, dpart[tid][c][0]);
            d2 = fminf(d2, dpart[tid][c][1]);
        }
        const float mu = (d1 - d2) / (d1 + d2 + EPSF);
        const float alpha = logf(1.0f + (float)tval[0]);
        float s = 1.0f / (1.0f + expf(-alpha * mu));
        for (int off = 16; off; off >>= 1) s += __shfl_down(s, off);
        if (tid == 0) bsum[blockIdx.x] = s;
    }
}

__global__ __launch_bounds__(256) void final_sum(
    const float* __restrict__ bsum, float* __restrict__ out)
{
    float s = bsum[threadIdx.x];
    for (int off = 32; off; off >>= 1) s += __shfl_down(s, off);
    __shared__ float red[4];
    if ((threadIdx.x & 63) == 0) red[threadIdx.x >> 6] = s;
    __syncthreads();
    if (threadIdx.x == 0) out[0] = (red[0] + red[1] + red[2] + red[3]) * (1.0f / (float)NS);
}

extern "C" void kernel_launch(void* const* d_in, const int* in_sizes, int n_in,
                              void* d_out, int out_size, void* d_ws, size_t ws_size,
                              hipStream_t stream) {
    const float* x      = (const float*)d_in[0];
    const int*   y      = (const int*)d_in[1];
    const int*   tval   = (const int*)d_in[2];
    const float* protos = (const float*)d_in[3];
    float* out = (float*)d_out;

    char* ws = (char*)d_ws;
    unsigned short* pb = (unsigned short*)(ws);                    // 1 MB
    float* psq  = (float*)(ws + (size_t)NP * DD * 2);              // 2 KB
    float* bsum = psq + NP;                                        // 1 KB

    prep_protos<<<NP, 256, 0, stream>>>(protos, pb, psq);
    glvq_fused<<<NS / MT, 512, 0, stream>>>(x, pb, psq, y, tval, bsum);
    final_sum<<<1, 256, 0, stream>>>(bsum, out);
}

// Round 6
// 39.588 us; speedup vs baseline: 1.0352x; 1.0352x over previous
//
#include <hip/hip_runtime.h>
#include <hip/hip_bf16.h>
#include <math.h>
#include <stdint.h>

#define NS 8192       // samples
#define DD 1024       // feature dim
#define NP 512        // prototypes
#define BK 64         // K-chunk
#define MT 64         // M rows per block
#define NT 128        // N cols per block
#define NPARTS 8      // 4 N-blocks * 2 wave-col-halves
#define EPSF 1e-9f
#define BIGF 3.0e38f

typedef __attribute__((ext_vector_type(8))) short bf16x8;
typedef __attribute__((ext_vector_type(4))) float f32x4;

__device__ inline unsigned short f32_to_bf16(float f) {
    uint32_t u = __builtin_bit_cast(uint32_t, f);
    uint32_t r = (u + 0x7FFFu + ((u >> 16) & 1u)) >> 16;
    return (unsigned short)r;
}

__device__ inline uint32_t cvt_pk(float lo, float hi) {
    uint32_t r;
    asm("v_cvt_pk_bf16_f32 %0, %1, %2" : "=v"(r) : "v"(lo), "v"(hi));
    return r;
}

// protos f32 -> bf16 (pb) + exact f32 psq. One block per prototype row.
__global__ __launch_bounds__(256) void prep_protos(
    const float* __restrict__ protos,
    unsigned short* __restrict__ pb, float* __restrict__ psq)
{
    const int row = blockIdx.x;
    const int t = threadIdx.x;
    float4 v = ((const float4*)(protos + (size_t)row * DD))[t];
    float ss = v.x * v.x + v.y * v.y + v.z * v.z + v.w * v.w;
    ushort4 o;
    o.x = f32_to_bf16(v.x); o.y = f32_to_bf16(v.y);
    o.z = f32_to_bf16(v.z); o.w = f32_to_bf16(v.w);
    ((ushort4*)(pb + (size_t)row * DD))[t] = o;
    for (int off = 32; off; off >>= 1) ss += __shfl_down(ss, off);
    __shared__ float red[4];
    if ((t & 63) == 0) red[t >> 6] = ss;
    __syncthreads();
    if (t == 0) psq[row] = red[0] + red[1] + red[2] + red[3];
}

// Fused GEMM+min: 64x128 tile, BK=64, 4 waves (2M x 2N, wave-tile 32x64), dbuf.
// x read f32 (once), cvt->bf16 in-reg (cvt_pk), exact xsq on the fly.
// B via global_load_lds + XOR-swizzle involution. Grid 512 (2 blocks/CU),
// XCD-bijective: per XCD 16 M-blocks x 4 N-blocks.
__global__ __launch_bounds__(256) void glvq_fused(
    const float* __restrict__ x, const unsigned short* __restrict__ pb,
    const float* __restrict__ psq, const int* __restrict__ y,
    float* __restrict__ d1p, float* __restrict__ d2p)
{
    __shared__ unsigned short As[2][MT * BK];   // 2 x 8 KB
    __shared__ unsigned short Bs[2][NT * BK];   // 2 x 16 KB
    __shared__ float xs_l[MT];

    const int tid  = threadIdx.x;
    const int lane = tid & 63;
    const int wid  = tid >> 6;        // 0..3
    const int wr = wid >> 1;          // 0..1 -> rows wr*32
    const int wc = wid & 1;           // 0..1 -> cols wc*64
    const int d    = blockIdx.x;      // 0..511
    const int xcd  = d & 7;
    const int slot = d >> 3;          // 0..63
    const int mb   = xcd * 16 + (slot & 15);   // 0..127
    const int nb   = slot >> 4;                // 0..3
    const int m0   = mb * MT;
    const int n0   = nb * NT;

    const int srow   = lane >> 3;                 // 0..7
    const int scol16 = (lane & 7) ^ srow;         // pre-swizzled B source chunk
    const int sub = lane & 15, g = lane >> 4;

    // A staging: thread t covers row t>>2, chunks (t&3)*2 .. +1 (16 bf16 = 32 f32 bytes each)
    const int arow = tid >> 2;        // 0..63
    const int acb  = (tid & 3) * 2;   // chunk base 0,2,4,6
    const float* xrow = x + (size_t)(m0 + arow) * DD;

    f32x4 acc[2][4] = {};
    float xss = 0.0f;
    float4 av[4];                     // 2 chunks x 2 float4

    auto stageB = [&](int buf, int kt) {
        const int k0 = kt * BK;
#pragma unroll
        for (int j = 0; j < 4; ++j) {
            const int c = wid * 4 + j;            // 0..15, 8 B-rows each
            const unsigned short* gb = pb + (size_t)(n0 + c * 8 + srow) * DD + k0 + scol16 * 8;
            __builtin_amdgcn_global_load_lds(
                (const __attribute__((address_space(1))) void*)gb,
                (__attribute__((address_space(3))) void*)((char*)&Bs[buf][0] + c * 1024),
                16, 0, 0);
        }
    };
    auto loadA = [&](int kt) {
#pragma unroll
        for (int j = 0; j < 2; ++j) {
            const float* p = xrow + kt * BK + (acb + j) * 8;
            av[2 * j]     = *(const float4*)(p);
            av[2 * j + 1] = *(const float4*)(p + 4);
        }
    };
    auto writeA = [&](int buf) {
#pragma unroll
        for (int j = 0; j < 2; ++j) {
            float4 u = av[2 * j], w = av[2 * j + 1];
            xss += u.x * u.x + u.y * u.y + u.z * u.z + u.w * u.w
                 + w.x * w.x + w.y * w.y + w.z * w.z + w.w * w.w;
            uint4 o;
            o.x = cvt_pk(u.x, u.y); o.y = cvt_pk(u.z, u.w);
            o.z = cvt_pk(w.x, w.y); o.w = cvt_pk(w.z, w.w);
            const int c = acb + j;
            *(uint4*)((char*)&As[buf][0] + arow * 128 + ((c ^ (arow & 7)) * 16)) = o;
        }
    };
    auto compute = [&](int buf) {
#pragma unroll
        for (int kk = 0; kk < 2; ++kk) {
            bf16x8 a[2], b[4];
#pragma unroll
            for (int m = 0; m < 2; ++m) {
                const int rowa = wr * 32 + m * 16 + sub;
                const int c16 = (kk * 4 + g) ^ (rowa & 7);
                a[m] = *(const bf16x8*)((const char*)&As[buf][0] + rowa * 128 + c16 * 16);
            }
#pragma unroll
            for (int n = 0; n < 4; ++n) {
                const int rowb = wc * 64 + n * 16 + sub;
                const int c16 = (kk * 4 + g) ^ (rowb & 7);
                b[n] = *(const bf16x8*)((const char*)&Bs[buf][0] + rowb * 128 + c16 * 16);
            }
#pragma unroll
            for (int m = 0; m < 2; ++m)
#pragma unroll
                for (int n = 0; n < 4; ++n)
                    acc[m][n] = __builtin_amdgcn_mfma_f32_16x16x32_bf16(a[m], b[n], acc[m][n], 0, 0, 0);
        }
    };

    // prologue
    loadA(0); stageB(0, 0); writeA(0);
    __syncthreads();

    int cur = 0;
#pragma unroll 1
    for (int kt = 0; kt < DD / BK - 1; ++kt) {
        stageB(cur ^ 1, kt + 1);    // issue next B (in flight through compute)
        loadA(kt + 1);              // issue next A f32 loads
        compute(cur);
        writeA(cur ^ 1);
        __syncthreads();
        cur ^= 1;
    }
    compute(cur);

    // exact xsq: reduce the 4 staging threads of each row
    xss += __shfl_xor(xss, 1);
    xss += __shfl_xor(xss, 2);
    if ((tid & 3) == 0) xs_l[arow] = xss;
    __syncthreads();

    // ---- epilogue: masked mins over this wave's 64 cols ----
    float psqv[4];
    int   lab[4];
#pragma unroll
    for (int n = 0; n < 4; ++n) {
        const int col = n0 + wc * 64 + n * 16 + sub;
        psqv[n] = psq[col];
        lab[n]  = col >> 2;
    }
    const int part = nb * 2 + wc;
#pragma unroll
    for (int m = 0; m < 2; ++m) {
#pragma unroll
        for (int r = 0; r < 4; ++r) {
            const int rl = wr * 32 + m * 16 + g * 4 + r;
            const float xs = xs_l[rl];
            const int yy = y[m0 + rl];
            float d1 = BIGF, d2 = BIGF;
#pragma unroll
            for (int n = 0; n < 4; ++n) {
                const float dist = xs + psqv[n] - 2.0f * acc[m][n][r];
                if (lab[n] == yy) d1 = fminf(d1, dist);
                else              d2 = fminf(d2, dist);
            }
            for (int off = 8; off; off >>= 1) {
                d1 = fminf(d1, __shfl_xor(d1, off));
                d2 = fminf(d2, __shfl_xor(d2, off));
            }
            if (sub == 0) {
                d1p[part * NS + m0 + rl] = d1;
                d2p[part * NS + m0 + rl] = d2;
            }
        }
    }
}

__global__ __launch_bounds__(256) void finalize_kernel(
    const float* __restrict__ d1p, const float* __restrict__ d2p,
    const int* __restrict__ tval, float* __restrict__ bsum)
{
    const int row = blockIdx.x * 256 + threadIdx.x;
    float d1 = BIGF, d2 = BIGF;
#pragma unroll
    for (int p = 0; p < NPARTS; ++p) {
        d1 = fminf(d1, d1p[p * NS + row]);
        d2 = fminf(d2, d2p[p * NS + row]);
    }
    const float mu = (d1 - d2) / (d1 + d2 + EPSF);
    const float alpha = logf(1.0f + (float)tval[0]);
    float s = 1.0f / (1.0f + expf(-alpha * mu));
    for (int off = 32; off; off >>= 1) s += __shfl_down(s, off);
    __shared__ float red[4];
    if ((threadIdx.x & 63) == 0) red[threadIdx.x >> 6] = s;
    __syncthreads();
    if (threadIdx.x == 0) bsum[blockIdx.x] = red[0] + red[1] + red[2] + red[3];
}

__global__ void final_sum(const float* __restrict__ bsum, float* __restrict__ out) {
    float s = (threadIdx.x < NS / 256) ? bsum[threadIdx.x] : 0.0f;
    for (int off = 32; off; off >>= 1) s += __shfl_down(s, off);
    if (threadIdx.x == 0) out[0] = s * (1.0f / (float)NS);
}

extern "C" void kernel_launch(void* const* d_in, const int* in_sizes, int n_in,
                              void* d_out, int out_size, void* d_ws, size_t ws_size,
                              hipStream_t stream) {
    const float* x      = (const float*)d_in[0];
    const int*   y      = (const int*)d_in[1];
    const int*   tval   = (const int*)d_in[2];
    const float* protos = (const float*)d_in[3];
    float* out = (float*)d_out;

    char* ws = (char*)d_ws;
    unsigned short* pb = (unsigned short*)(ws);                    // 1 MB
    float* psq  = (float*)(ws + (size_t)NP * DD * 2);              // 2 KB
    float* d1p  = psq + NP;                                        // 256 KB
    float* d2p  = d1p + (size_t)NPARTS * NS;                       // 256 KB
    float* bsum = d2p + (size_t)NPARTS * NS;                       // 128 B

    prep_protos<<<NP, 256, 0, stream>>>(protos, pb, psq);
    glvq_fused<<<(NS / MT) * (NP / NT), 256, 0, stream>>>(x, pb, psq, y, d1p, d2p);
    finalize_kernel<<<NS / 256, 256, 0, stream>>>(d1p, d2p, tval, bsum);
    final_sum<<<1, 64, 0, stream>>>(bsum, out);
}

// Round 7
// 34.916 us; speedup vs baseline: 1.1738x; 1.1338x over previous
//
#include <hip/hip_runtime.h>
#include <hip/hip_bf16.h>
#include <math.h>
#include <stdint.h>

#define NS 8192       // samples
#define DD 1024       // feature dim
#define NP 512        // prototypes
#define BK 64         // K-chunk
#define MT 64         // M rows per block
#define NT 128        // N cols per block
#define NPARTS 8      // 4 N-blocks * 2 wave-col-halves
#define EPSF 1e-9f
#define BIGF 3.0e38f

typedef __attribute__((ext_vector_type(8))) short bf16x8;
typedef __attribute__((ext_vector_type(4))) float f32x4;

__device__ inline unsigned short f32_to_bf16(float f) {
    uint32_t u = __builtin_bit_cast(uint32_t, f);
    uint32_t r = (u + 0x7FFFu + ((u >> 16) & 1u)) >> 16;
    return (unsigned short)r;
}

__device__ inline uint32_t cvt_pk(float lo, float hi) {
    uint32_t r;
    asm("v_cvt_pk_bf16_f32 %0, %1, %2" : "=v"(r) : "v"(lo), "v"(hi));
    return r;
}

// protos f32 -> bf16 (pb) + exact f32 psq. One block per prototype row.
__global__ __launch_bounds__(256) void prep_protos(
    const float* __restrict__ protos,
    unsigned short* __restrict__ pb, float* __restrict__ psq)
{
    const int row = blockIdx.x;
    const int t = threadIdx.x;
    float4 v = ((const float4*)(protos + (size_t)row * DD))[t];
    float ss = v.x * v.x + v.y * v.y + v.z * v.z + v.w * v.w;
    ushort4 o;
    o.x = f32_to_bf16(v.x); o.y = f32_to_bf16(v.y);
    o.z = f32_to_bf16(v.z); o.w = f32_to_bf16(v.w);
    ((ushort4*)(pb + (size_t)row * DD))[t] = o;
    for (int off = 32; off; off >>= 1) ss += __shfl_down(ss, off);
    __shared__ float red[4];
    if ((t & 63) == 0) red[t >> 6] = ss;
    __syncthreads();
    if (t == 0) psq[row] = red[0] + red[1] + red[2] + red[3];
}

// Fused GEMM+min, counted-vmcnt pipeline (T4): per iter, B(kt+1) and A(kt+1)
// stay in flight across the barrier; only B(kt) is drained (vmcnt(4)).
// 64x128 tile, BK=64, 4 waves (2Mx2N), XOR-swizzled LDS, grid 512 (2/CU).
__global__ __launch_bounds__(256, 2) void glvq_fused(
    const float* __restrict__ x, const unsigned short* __restrict__ pb,
    const float* __restrict__ psq, const int* __restrict__ y,
    float* __restrict__ d1p, float* __restrict__ d2p)
{
    __shared__ unsigned short As[2][MT * BK];   // 2 x 8 KB
    __shared__ unsigned short Bs[2][NT * BK];   // 2 x 16 KB
    __shared__ float xs_l[MT];

    const int tid  = threadIdx.x;
    const int lane = tid & 63;
    const int wid  = tid >> 6;        // 0..3
    const int wr = wid >> 1;
    const int wc = wid & 1;
    const int d    = blockIdx.x;      // 0..511
    const int xcd  = d & 7;
    const int slot = d >> 3;
    const int mb   = xcd * 16 + (slot & 15);
    const int nb   = slot >> 4;
    const int m0   = mb * MT;
    const int n0   = nb * NT;

    const int srow   = lane >> 3;
    const int scol16 = (lane & 7) ^ srow;
    const int sub = lane & 15, g = lane >> 4;

    // A staging: thread t covers row t>>2, chunks (t&3)*2 .. +1
    const int arow = tid >> 2;
    const int acb  = (tid & 3) * 2;
    const float* xrow = x + (size_t)(m0 + arow) * DD;

    f32x4 acc[2][4] = {};
    float xss = 0.0f;
    float4 av[4];

    auto stageB = [&](int buf, int kt) {
        const int k0 = kt * BK;
#pragma unroll
        for (int j = 0; j < 4; ++j) {
            const int c = wid * 4 + j;
            const unsigned short* gb = pb + (size_t)(n0 + c * 8 + srow) * DD + k0 + scol16 * 8;
            __builtin_amdgcn_global_load_lds(
                (const __attribute__((address_space(1))) void*)gb,
                (__attribute__((address_space(3))) void*)((char*)&Bs[buf][0] + c * 1024),
                16, 0, 0);
        }
    };
    auto loadA = [&](int kt) {
#pragma unroll
        for (int j = 0; j < 2; ++j) {
            const float* p = xrow + kt * BK + (acb + j) * 8;
            av[2 * j]     = *(const float4*)(p);
            av[2 * j + 1] = *(const float4*)(p + 4);
        }
    };
    auto writeA = [&](int buf) {
#pragma unroll
        for (int j = 0; j < 2; ++j) {
            float4 u = av[2 * j], w = av[2 * j + 1];
            xss += u.x * u.x + u.y * u.y + u.z * u.z + u.w * u.w
                 + w.x * w.x + w.y * w.y + w.z * w.z + w.w * w.w;
            uint4 o;
            o.x = cvt_pk(u.x, u.y); o.y = cvt_pk(u.z, u.w);
            o.z = cvt_pk(w.x, w.y); o.w = cvt_pk(w.z, w.w);
            const int c = acb + j;
            *(uint4*)((char*)&As[buf][0] + arow * 128 + ((c ^ (arow & 7)) * 16)) = o;
        }
    };
    auto compute = [&](int buf) {
#pragma unroll
        for (int kk = 0; kk < 2; ++kk) {
            bf16x8 a[2], b[4];
#pragma unroll
            for (int m = 0; m < 2; ++m) {
                const int rowa = wr * 32 + m * 16 + sub;
                const int c16 = (kk * 4 + g) ^ (rowa & 7);
                a[m] = *(const bf16x8*)((const char*)&As[buf][0] + rowa * 128 + c16 * 16);
            }
#pragma unroll
            for (int n = 0; n < 4; ++n) {
                const int rowb = wc * 64 + n * 16 + sub;
                const int c16 = (kk * 4 + g) ^ (rowb & 7);
                b[n] = *(const bf16x8*)((const char*)&Bs[buf][0] + rowb * 128 + c16 * 16);
            }
#pragma unroll
            for (int m = 0; m < 2; ++m)
#pragma unroll
                for (int n = 0; n < 4; ++n)
                    acc[m][n] = __builtin_amdgcn_mfma_f32_16x16x32_bf16(a[m], b[n], acc[m][n], 0, 0, 0);
        }
    };

    // prologue: A(0) issued first (older than B(0)) so writeA's reg-dep wait
    // leaves B(0) in flight.
    loadA(0);
    stageB(0, 0);

    int cur = 0;
#pragma unroll 1
    for (int kt = 0; kt < DD / BK - 1; ++kt) {
        writeA(cur);              // consumes av = A(kt); ds_write (lgkm)
        loadA(kt + 1);            // A(kt+1) issue (stays in flight past barrier)
        // drain exactly B(kt) (4 oldest); keep A(kt+1) (4 newest) outstanding
        asm volatile("s_waitcnt vmcnt(4) lgkmcnt(0)" ::: "memory");
        __builtin_amdgcn_s_barrier();
        stageB(cur ^ 1, kt + 1);  // B(kt+1) into freed buffer (covered by MFMA below)
        compute(cur);
        cur ^= 1;
    }
    // peeled last tile: nothing left to prefetch
    writeA(cur);
    asm volatile("s_waitcnt vmcnt(0) lgkmcnt(0)" ::: "memory");
    __builtin_amdgcn_s_barrier();
    compute(cur);

    // exact xsq: reduce the 4 staging threads of each row
    xss += __shfl_xor(xss, 1);
    xss += __shfl_xor(xss, 2);
    if ((tid & 3) == 0) xs_l[arow] = xss;
    __syncthreads();

    // ---- epilogue: masked mins over this wave's 64 cols ----
    float psqv[4];
    int   lab[4];
#pragma unroll
    for (int n = 0; n < 4; ++n) {
        const int col = n0 + wc * 64 + n * 16 + sub;
        psqv[n] = psq[col];
        lab[n]  = col >> 2;
    }
    const int part = nb * 2 + wc;
#pragma unroll
    for (int m = 0; m < 2; ++m) {
#pragma unroll
        for (int r = 0; r < 4; ++r) {
            const int rl = wr * 32 + m * 16 + g * 4 + r;
            const float xs = xs_l[rl];
            const int yy = y[m0 + rl];
            float d1 = BIGF, d2 = BIGF;
#pragma unroll
            for (int n = 0; n < 4; ++n) {
                const float dist = xs + psqv[n] - 2.0f * acc[m][n][r];
                if (lab[n] == yy) d1 = fminf(d1, dist);
                else              d2 = fminf(d2, dist);
            }
            for (int off = 8; off; off >>= 1) {
                d1 = fminf(d1, __shfl_xor(d1, off));
                d2 = fminf(d2, __shfl_xor(d2, off));
            }
            if (sub == 0) {
                d1p[part * NS + m0 + rl] = d1;
                d2p[part * NS + m0 + rl] = d2;
            }
        }
    }
}

__global__ __launch_bounds__(256) void finalize_kernel(
    const float* __restrict__ d1p, const float* __restrict__ d2p,
    const int* __restrict__ tval, float* __restrict__ bsum)
{
    const int row = blockIdx.x * 256 + threadIdx.x;
    float d1 = BIGF, d2 = BIGF;
#pragma unroll
    for (int p = 0; p < NPARTS; ++p) {
        d1 = fminf(d1, d1p[p * NS + row]);
        d2 = fminf(d2, d2p[p * NS + row]);
    }
    const float mu = (d1 - d2) / (d1 + d2 + EPSF);
    const float alpha = logf(1.0f + (float)tval[0]);
    float s = 1.0f / (1.0f + expf(-alpha * mu));
    for (int off = 32; off; off >>= 1) s += __shfl_down(s, off);
    __shared__ float red[4];
    if ((threadIdx.x & 63) == 0) red[threadIdx.x >> 6] = s;
    __syncthreads();
    if (threadIdx.x == 0) bsum[blockIdx.x] = red[0] + red[1] + red[2] + red[3];
}

__global__ void final_sum(const float* __restrict__ bsum, float* __restrict__ out) {
    float s = (threadIdx.x < NS / 256) ? bsum[threadIdx.x] : 0.0f;
    for (int off = 32; off; off >>= 1) s += __shfl_down(s, off);
    if (threadIdx.x == 0) out[0] = s * (1.0f / (float)NS);
}

extern "C" void kernel_launch(void* const* d_in, const int* in_sizes, int n_in,
                              void* d_out, int out_size, void* d_ws, size_t ws_size,
                              hipStream_t stream) {
    const float* x      = (const float*)d_in[0];
    const int*   y      = (const int*)d_in[1];
    const int*   tval   = (const int*)d_in[2];
    const float* protos = (const float*)d_in[3];
    float* out = (float*)d_out;

    char* ws = (char*)d_ws;
    unsigned short* pb = (unsigned short*)(ws);                    // 1 MB
    float* psq  = (float*)(ws + (size_t)NP * DD * 2);              // 2 KB
    float* d1p  = psq + NP;                                        // 256 KB
    float* d2p  = d1p + (size_t)NPARTS * NS;                       // 256 KB
    float* bsum = d2p + (size_t)NPARTS * NS;                       // 128 B

    prep_protos<<<NP, 256, 0, stream>>>(protos, pb, psq);
    glvq_fused<<<(NS / MT) * (NP / NT), 256, 0, stream>>>(x, pb, psq, y, d1p, d2p);
    finalize_kernel<<<NS / 256, 256, 0, stream>>>(d1p, d2p, tval, bsum);
    final_sum<<<1, 64, 0, stream>>>(bsum, out);
}